// Round 7
// baseline (132.229 us; speedup 1.0000x reference)
//
#include <hip/hip_runtime.h>

// 5x5 median, reflect padding, 16x3x512x512 fp32.
// Round-7 = Round-6 compute (passing, absmax 7.8e-3) with the GRID fixed.
// Diagnosis from R3-R6 invariance (55us, VALUBusy ~56% across register/LDS/asm
// variants): occupancy 41-55% despite VGPR=40/no-LDS allowing 100% -> grid
// 3072 blocks = 1.5x the 2048 co-resident capacity; half-empty second round +
// dependency-chain bubbles with only ~3.7 waves/SIMD = the stall.
// Fix: R=4 rows/thread -> 6144 blocks = exactly 3 full co-residency rounds;
// __launch_bounds__(256,8) keeps VGPR<=64 so 8 waves/SIMD stays legal.
// Algorithm per output (unchanged): rotating sorted-row buffer (9-CAS sort5,
// amortized over vertical slide) -> 5 column sorts (preserves row sortedness)
// -> rank-prune doubly-sorted 5x5 to 13 candidates ((i+1)(j+1)>=14 or
// (5-i)(5-j)>=14 excluded) -> 7th-smallest-of-13 forgetful selection
// (3x MINMAX8, 2x MINMAX5, med3). Packed f16: 2 pixels/lane.

typedef _Float16 h2 __attribute__((ext_vector_type(2)));

static __device__ __forceinline__ h2 pk_min(h2 a, h2 b) {
    h2 r;
    asm("v_pk_min_f16 %0, %1, %2" : "=v"(r) : "v"(a), "v"(b));
    return r;
}
static __device__ __forceinline__ h2 pk_max(h2 a, h2 b) {
    h2 r;
    asm("v_pk_max_f16 %0, %1, %2" : "=v"(r) : "v"(a), "v"(b));
    return r;
}

static __device__ __forceinline__ h2 pack2(float a, float b) {
    return __builtin_bit_cast(h2, __builtin_amdgcn_cvt_pkrtz(a, b));
}

#define CAS(a, b) do { h2 _mn = pk_min((a), (b)); (b) = pk_max((a), (b)); (a) = _mn; } while (0)

// optimal 9-CAS 5-sorter
static __device__ __forceinline__ void sort5(h2 &e0, h2 &e1, h2 &e2, h2 &e3, h2 &e4) {
    CAS(e0, e1); CAS(e3, e4); CAS(e2, e4); CAS(e2, e3); CAS(e0, e3);
    CAS(e0, e2); CAS(e1, e4); CAS(e1, e3); CAS(e1, e2);
}

// global min -> w0, global max -> w7 (10 CAS)
#define MINMAX8(w0, w1, w2, w3, w4, w5, w6, w7) do {      \
    CAS(w0, w1); CAS(w2, w3); CAS(w4, w5); CAS(w6, w7);   \
    CAS(w0, w2); CAS(w4, w6); CAS(w0, w4);                \
    CAS(w1, w3); CAS(w5, w7); CAS(w3, w7); } while (0)

// global min -> v0, global max -> v4 (6 CAS)
#define MINMAX5(v0, v1, v2, v3, v4) do {                  \
    CAS(v0, v1); CAS(v2, v3); CAS(v0, v2); CAS(v1, v3);   \
    CAS(v0, v4); CAS(v3, v4); } while (0)

// 7th smallest of 13 (forgetful selection; rank-safety per header comment)
static __device__ __forceinline__ h2 sel7of13(h2 c0, h2 c1, h2 c2, h2 c3, h2 c4, h2 c5, h2 c6,
                                              h2 c7, h2 c8, h2 c9, h2 c10, h2 c11, h2 c12) {
    MINMAX8(c0, c1, c2, c3, c4, c5, c6, c7); c0 = c8;  c7 = c9;
    MINMAX8(c0, c1, c2, c3, c4, c5, c6, c7); c0 = c10; c7 = c11;
    MINMAX8(c0, c1, c2, c3, c4, c5, c6, c7); c0 = c12;
    MINMAX5(c0, c1, c2, c3, c4); c0 = c5; c4 = c6;
    MINMAX5(c0, c1, c2, c3, c4);
    CAS(c1, c2); CAS(c2, c3); CAS(c1, c2);
    return c2;
}

static __device__ __forceinline__ int refl(int v, int n) {
    v = (v < 0) ? (-v - 1) : v;
    return (v >= n) ? (2 * n - 1 - v) : v;
}

static __device__ __forceinline__ void load_sorted_row(h2 (&dst)[5], const float* __restrict__ rp,
                                                       const int (&xo)[6]) {
    // halves: .x = pixel at x0 (window cols f0..f4), .y = pixel at x0+1 (f1..f5)
    float f0 = rp[xo[0]], f1 = rp[xo[1]], f2 = rp[xo[2]],
          f3 = rp[xo[3]], f4 = rp[xo[4]], f5 = rp[xo[5]];
    dst[0] = pack2(f0, f1);
    dst[1] = pack2(f1, f2);
    dst[2] = pack2(f2, f3);
    dst[3] = pack2(f3, f4);
    dst[4] = pack2(f4, f5);
    sort5(dst[0], dst[1], dst[2], dst[3], dst[4]);
}

constexpr int W = 512, H = 512, R = 4;   // R=4: 6144 blocks = 3 full rounds

__global__ __launch_bounds__(256, 8) void median5x5_kernel(const float* __restrict__ in,
                                                           float* __restrict__ out) {
    const int tx = blockIdx.x * 64 + threadIdx.x;     // 0..255 -> 2 pixels each
    const int x0 = 2 * tx;
    const int ystrip = blockIdx.y * 4 + threadIdx.y;  // 0..127
    const int y0 = ystrip * R;
    const size_t plane = (size_t)blockIdx.z * ((size_t)H * W);
    const float* __restrict__ p = in + plane;
    float* __restrict__ q = out + plane;

    int xo[6];
    #pragma unroll
    for (int d = 0; d < 6; ++d) xo[d] = refl(x0 - 2 + d, W);

    h2 rows[5][5];  // rotating buffer of sorted rows; fully unrolled -> registers

    #pragma unroll
    for (int k = 0; k < 4; ++k)
        load_sorted_row(rows[k], p + (size_t)refl(y0 - 2 + k, H) * W, xo);

    #pragma unroll
    for (int t = 0; t < R; ++t) {
        load_sorted_row(rows[(4 + t) % 5], p + (size_t)refl(y0 + 2 + t, H) * W, xo);

        h2 (&s0)[5] = rows[(t + 0) % 5];
        h2 (&s1)[5] = rows[(t + 1) % 5];
        h2 (&s2)[5] = rows[(t + 2) % 5];
        h2 (&s3)[5] = rows[(t + 3) % 5];
        h2 (&s4)[5] = rows[(t + 4) % 5];

        // column sorts (vertical order irrelevant; preserves row sortedness)
        h2 a0=s0[0], a1=s1[0], a2=s2[0], a3=s3[0], a4=s4[0]; sort5(a0,a1,a2,a3,a4);
        h2 b0=s0[1], b1=s1[1], b2=s2[1], b3=s3[1], b4=s4[1]; sort5(b0,b1,b2,b3,b4);
        h2 c0=s0[2], c1=s1[2], c2=s2[2], c3=s3[2], c4=s4[2]; sort5(c0,c1,c2,c3,c4);
        h2 d0=s0[3], d1=s1[3], d2=s2[3], d3=s3[3], d4=s4[3]; sort5(d0,d1,d2,d3,d4);
        h2 e0=s0[4], e1=s1[4], e2=s2[4], e3=s3[4], e4=s4[4]; sort5(e0,e1,e2,e3,e4);
        (void)a0; (void)a1; (void)a2; (void)b0; (void)b1; (void)c0; (void)c4;
        (void)d3; (void)d4; (void)e2; (void)e3; (void)e4;

        // 13 candidates (pos-in-col, col): (0,3)(0,4)(1,2)(1,3)(1,4)
        // (2,1)(2,2)(2,3)(3,0)(3,1)(3,2)(4,0)(4,1)
        h2 med = sel7of13(d0, e0, c1, d1, e1, b2, c2, d2, a3, b3, c3, a4, b4);

        float2 o;
        o.x = (float)med.x;
        o.y = (float)med.y;
        *reinterpret_cast<float2*>(q + (size_t)(y0 + t) * W + x0) = o;
    }
}

extern "C" void kernel_launch(void* const* d_in, const int* in_sizes, int n_in,
                              void* d_out, int out_size, void* d_ws, size_t ws_size,
                              hipStream_t stream) {
    const float* in = (const float*)d_in[0];
    float* out = (float*)d_out;
    dim3 block(64, 4, 1);
    dim3 grid(512 / (64 * 2), 512 / (4 * R), 16 * 3);   // 4 x 32 x 48 = 6144
    hipLaunchKernelGGL(median5x5_kernel, grid, block, 0, stream, in, out);
}

// Round 8
// 126.104 us; speedup vs baseline: 1.0486x; 1.0486x over previous
//
#include <hip/hip_runtime.h>

// 5x5 median, reflect padding, 16x3x512x512 fp32.
// Round-8 = Round-6 structure (R=8 vertical slide, rotating sorted-row buffer,
// direct global loads, 2 packed-f16 px/lane) with both post-row stages reduced
// by provable partial networks (evidence: time ~ 0.475us x CAS/2px across
// R1/R6/R7; only op count moves time).
//  Stage 1 (columns): partial sorts producing exactly the needed ranks:
//    col0 top-2 (a3,a4), col1 top-3 (b2..b4), col2 mid-3 (c1..c3),
//    col3 bottom-3 (d0..d2), col4 bottom-2 (e0,e1).  [~33 CAS-eq vs 45]
//  Stage 2 (selection, rank-7 of the 13 candidates of the doubly-sorted 5x5):
//    merge (d0,d1,d2)+(e0,e1)->S5 (3 CAS; d0<=e0 by row-sort lemma),
//    merge (b2,b3,b4)+(a3,a4)->T5 (3 CAS; a3<=b3, a4<=b4),
//    bitonic split CAS(S_i,T_4-i) -> L=ranks1..5, H=ranks6..10 (5 CAS),
//    top-2(L)=ranks4,5 + bottom-2(H)=ranks6,7 (ranks 1-3 < median, 8-10 > it),
//    median7 of chains (W4<=W5<=W6<=W7) + (c1<=c2<=c3): trim ends + med5
//    with one pre-sorted pair.                         [~28 CAS-eq vs 45]
// All primitives proved in-session (2nd-of-4 = max(min(h0,h1),max(l0,l1));
// insertion chains; merge-of-sorted-pairs; bitonic split L_i<=H_k for all i,k).

typedef _Float16 h2 __attribute__((ext_vector_type(2)));

static __device__ __forceinline__ h2 MN(h2 a, h2 b) { return __builtin_elementwise_min(a, b); }
static __device__ __forceinline__ h2 MX(h2 a, h2 b) { return __builtin_elementwise_max(a, b); }

static __device__ __forceinline__ h2 pack2(float a, float b) {
    return __builtin_bit_cast(h2, __builtin_amdgcn_cvt_pkrtz(a, b));
}

#define CAS(a, b) do { h2 _t = MN(a, b); (b) = MX(a, b); (a) = _t; } while (0)

// optimal 9-CAS 5-sorter (all outputs live -> full CAS)
static __device__ __forceinline__ void sort5(h2 &e0, h2 &e1, h2 &e2, h2 &e3, h2 &e4) {
    CAS(e0, e1); CAS(e3, e4); CAS(e2, e4); CAS(e2, e3); CAS(e0, e3);
    CAS(e0, e2); CAS(e1, e4); CAS(e1, e3); CAS(e1, e2);
}

// ---- partial rank selectors (proofs in header comment / session log) ----
// ordered top-2 of 5 -> (o3=2nd largest, o4=largest)
static __device__ __forceinline__ void top2of5(h2 z0, h2 z1, h2 z2, h2 z3, h2 z4,
                                               h2 &o3, h2 &o4) {
    h2 l0 = MN(z0, z1), h0 = MX(z0, z1), l1 = MN(z2, z3), h1 = MX(z2, z3);
    h2 mh = MN(h0, h1), Mh = MX(h0, h1);
    h2 p2 = MX(mh, MX(l0, l1));          // 2nd largest of z0..z3
    h2 m  = MN(Mh, z4); o4 = MX(Mh, z4);
    o3 = MX(p2, m);
}
// ordered bottom-2 of 5 -> (o0=smallest, o1=2nd smallest)
static __device__ __forceinline__ void bot2of5(h2 z0, h2 z1, h2 z2, h2 z3, h2 z4,
                                               h2 &o0, h2 &o1) {
    h2 l0 = MN(z0, z1), h0 = MX(z0, z1), l1 = MN(z2, z3), h1 = MX(z2, z3);
    h2 g = MN(l0, l1), G = MX(l0, l1);
    h2 q1 = MN(G, MN(h0, h1));           // 2nd smallest of z0..z3
    h2 M = MX(g, z4); o0 = MN(g, z4);
    o1 = MN(q1, M);
}
// ordered top-3 of 5 -> (o2<=o3<=o4)
static __device__ __forceinline__ void top3of5(h2 z0, h2 z1, h2 z2, h2 z3, h2 z4,
                                               h2 &o2, h2 &o3, h2 &o4) {
    h2 l0 = MN(z0, z1), h0 = MX(z0, z1), l1 = MN(z2, z3), h1 = MX(z2, z3);
    h2 G = MX(l0, l1);
    h2 sb = MN(h0, h1), S = MX(h0, h1);
    h2 p1 = MN(G, sb), p2 = MX(G, sb);   // ranks 1,2 of z0..z3 (rank0 dead)
    h2 m3 = MN(S, z4); o4 = MX(S, z4);
    h2 m2 = MN(p2, m3); o3 = MX(p2, m3);
    o2 = MX(p1, m2);
}
// ordered bottom-3 of 5 -> (o0<=o1<=o2)
static __device__ __forceinline__ void bot3of5(h2 z0, h2 z1, h2 z2, h2 z3, h2 z4,
                                               h2 &o0, h2 &o1, h2 &o2) {
    h2 l0 = MN(z0, z1), h0 = MX(z0, z1), l1 = MN(z2, z3), h1 = MX(z2, z3);
    h2 g = MN(l0, l1), G = MX(l0, l1);
    h2 mnH = MN(h0, h1);
    h2 p1 = MN(G, mnH), p2 = MX(G, mnH); // ranks 1,2 of z0..z3 (rank3 dead)
    o0 = MN(g, z4); h2 M0 = MX(g, z4);
    o1 = MN(p1, M0); h2 M1 = MX(p1, M0);
    o2 = MN(p2, M1);
}
// ordered middle-3 of 5 -> (o1<=o2<=o3) = ranks 1,2,3
static __device__ __forceinline__ void mid3of5(h2 z0, h2 z1, h2 z2, h2 z3, h2 z4,
                                               h2 &o1, h2 &o2, h2 &o3) {
    h2 l0 = MN(z0, z1), h0 = MX(z0, z1), l1 = MN(z2, z3), h1 = MX(z2, z3);
    h2 g = MN(l0, l1), G = MX(l0, l1);
    h2 sc = MN(h0, h1), S = MX(h0, h1);
    h2 mlow = MX(g, z4);                  // drop global min (MN(g,z4) dead)
    // bottom-3 ordered of {mlow, G, sc, S}: merge sorted pairs, drop top
    h2 al = MN(mlow, G), be = MX(mlow, G);
    o1 = MN(al, sc); h2 gam = MX(al, sc);
    h2 del = MN(be, S);                   // top (MX(be,S)) dead
    o2 = MN(gam, del); o3 = MX(gam, del);
}

static __device__ __forceinline__ int refl(int v, int n) {
    v = (v < 0) ? (-v - 1) : v;
    return (v >= n) ? (2 * n - 1 - v) : v;
}

static __device__ __forceinline__ void load_sorted_row(h2 (&dst)[5], const float* __restrict__ rp,
                                                       const int (&xo)[6]) {
    float f0 = rp[xo[0]], f1 = rp[xo[1]], f2 = rp[xo[2]],
          f3 = rp[xo[3]], f4 = rp[xo[4]], f5 = rp[xo[5]];
    dst[0] = pack2(f0, f1);
    dst[1] = pack2(f1, f2);
    dst[2] = pack2(f2, f3);
    dst[3] = pack2(f3, f4);
    dst[4] = pack2(f4, f5);
    sort5(dst[0], dst[1], dst[2], dst[3], dst[4]);
}

// median of 25 from 5 sorted rows (each ascending)
static __device__ __forceinline__ h2 median25(const h2 (&s0)[5], const h2 (&s1)[5],
                                              const h2 (&s2)[5], const h2 (&s3)[5],
                                              const h2 (&s4)[5]) {
    // Stage 1: needed column ranks (i=rank-in-column, j=col):
    h2 a3, a4; top2of5(s0[0], s1[0], s2[0], s3[0], s4[0], a3, a4);
    h2 b2, b3, b4; top3of5(s0[1], s1[1], s2[1], s3[1], s4[1], b2, b3, b4);
    h2 c1, c2, c3; mid3of5(s0[2], s1[2], s2[2], s3[2], s4[2], c1, c2, c3);
    h2 d0, d1, d2; bot3of5(s0[3], s1[3], s2[3], s3[3], s4[3], d0, d1, d2);
    h2 e0, e1; bot2of5(s0[4], s1[4], s2[4], s3[4], s4[4], e0, e1);

    // Stage 2a: S = merge (d0,d1,d2)+(e0,e1); d0<=e0 (row-0 sortedness)
    h2 S0 = d0;
    h2 S1 = MN(d1, e0), P = MX(d1, e0);
    h2 q = MN(d2, e1), S4 = MX(d2, e1);
    h2 S2 = MN(P, q), S3 = MX(P, q);
    // Stage 2b: T = merge (b2,b3,b4)+(a3,a4); a3<=b3, a4<=b4 (rows 3,4)
    h2 T4 = b4;
    h2 T0 = MN(b2, a3), U1 = MX(b2, a3);
    h2 vv = MN(b3, a4), T3 = MX(b3, a4);
    h2 T1 = MN(U1, vv), T2 = MX(U1, vv);
    // Stage 2c: bitonic split -> L = 5 smallest of S∪T, H = 5 largest
    h2 L0 = MN(S0, T4), H0 = MX(S0, T4);
    h2 L1 = MN(S1, T3), H1 = MX(S1, T3);
    h2 L2 = MN(S2, T2), H2 = MX(S2, T2);
    h2 L3 = MN(S3, T1), H3 = MX(S3, T1);
    h2 L4 = MN(S4, T0), H4 = MX(S4, T0);
    // Stage 2d: ranks 4,5 (top-2 of L) and 6,7 (bottom-2 of H) of S∪T
    h2 w4, w5; top2of5(L0, L1, L2, L3, L4, w4, w5);
    h2 w6, w7; bot2of5(H0, H1, H2, H3, H4, w6, w7);
    // Stage 2e: median of 7 = chains (w4<=w5<=w6<=w7) + (c1<=c2<=c3)
    h2 hi = MN(w7, c3);                   // drop max-of-7
    h2 lo = MX(w4, c1);                   // drop min-of-7
    // med5 of (lo, c2, hi, w5, w6), pair (w5<=w6) pre-sorted
    h2 t0 = MN(lo, c2), t1 = MX(lo, c2);
    h2 a3b = MX(t0, w5);                  // CAS(a0,a3): a0 dead
    h2 a1b = MN(t1, w6);                  // CAS(a1,a4): a4 dead
    h2 mn = MN(a1b, a3b), mx = MX(a1b, a3b);
    return MX(mn, MN(mx, hi));            // med3(a1b, hi, a3b)
}

constexpr int W = 512, H = 512, R = 8;

__global__ __launch_bounds__(256) void median5x5_kernel(const float* __restrict__ in,
                                                        float* __restrict__ out) {
    const int tx = blockIdx.x * 64 + threadIdx.x;     // 0..255 -> 2 pixels each
    const int x0 = 2 * tx;
    const int ystrip = blockIdx.y * 4 + threadIdx.y;  // 0..63
    const int y0 = ystrip * R;
    const size_t plane = (size_t)blockIdx.z * ((size_t)H * W);
    const float* __restrict__ p = in + plane;
    float* __restrict__ q = out + plane;

    int xo[6];
    #pragma unroll
    for (int d = 0; d < 6; ++d) xo[d] = refl(x0 - 2 + d, W);

    h2 rows[5][5];  // rotating buffer of sorted rows

    #pragma unroll
    for (int k = 0; k < 4; ++k)
        load_sorted_row(rows[k], p + (size_t)refl(y0 - 2 + k, H) * W, xo);

    #pragma unroll
    for (int t = 0; t < R; ++t) {
        load_sorted_row(rows[(4 + t) % 5], p + (size_t)refl(y0 + 2 + t, H) * W, xo);

        h2 med = median25(rows[(t + 0) % 5], rows[(t + 1) % 5], rows[(t + 2) % 5],
                          rows[(t + 3) % 5], rows[(t + 4) % 5]);

        float2 o;
        o.x = (float)med.x;
        o.y = (float)med.y;
        *reinterpret_cast<float2*>(q + (size_t)(y0 + t) * W + x0) = o;
    }
}

extern "C" void kernel_launch(void* const* d_in, const int* in_sizes, int n_in,
                              void* d_out, int out_size, void* d_ws, size_t ws_size,
                              hipStream_t stream) {
    const float* in = (const float*)d_in[0];
    float* out = (float*)d_out;
    dim3 block(64, 4, 1);
    dim3 grid(512 / (64 * 2), 512 / (4 * R), 16 * 3);
    hipLaunchKernelGGL(median5x5_kernel, grid, block, 0, stream, in, out);
}